// Round 1
// baseline (209.127 us; speedup 1.0000x reference)
//
#include <hip/hip_runtime.h>
#include <math.h>

#define NB 64
#define NP 8732
#define NC 81
#define NROWS (NB * NP)

// ws layout: acc[0]=class_pos_sum (double), acc[1]=sl1_sum (double),
//            *(uint*)(acc+2)=num_pos, bg_loss floats at byte offset 64.

__global__ __launch_bounds__(256) void mb_rows(
    const float* __restrict__ conf,
    const float* __restrict__ pred,
    const float* __restrict__ gt,
    const int*   __restrict__ labels,
    float* __restrict__ bg,
    double* __restrict__ acc)
{
    const int lane = threadIdx.x & 63;
    const int wid  = threadIdx.x >> 6;
    const int gw   = blockIdx.x * 4 + wid;   // 4 waves / 256-thread block
    const int nw   = gridDim.x * 4;

    double ce_sum = 0.0, sl1_sum = 0.0;
    unsigned int np = 0;

    for (int row = gw; row < NROWS; row += nw) {
        const float* rp = conf + (size_t)row * NC;
        float x0 = rp[lane];
        float x1 = (lane < NC - 64) ? rp[lane + 64] : -__builtin_inff();

        float m = fmaxf(x0, x1);
        #pragma unroll
        for (int o = 32; o; o >>= 1) m = fmaxf(m, __shfl_xor(m, o));

        float e = expf(x0 - m) + ((lane < NC - 64) ? expf(x1 - m) : 0.0f);
        #pragma unroll
        for (int o = 32; o; o >>= 1) e += __shfl_xor(e, o);

        float lse = m + logf(e);

        if (lane == 0) {
            bg[row] = lse - x0;              // -log_softmax[...,0]
            int lbl = labels[row];
            if (lbl > 0) {
                ce_sum += (double)(lse - rp[lbl]);
                np++;
                float4 pv = ((const float4*)pred)[row];
                float4 gv = ((const float4*)gt)[row];
                float d;
                d = fabsf(pv.x - gv.x); sl1_sum += (d < 1.0f) ? 0.5f * d * d : d - 0.5f;
                d = fabsf(pv.y - gv.y); sl1_sum += (d < 1.0f) ? 0.5f * d * d : d - 0.5f;
                d = fabsf(pv.z - gv.z); sl1_sum += (d < 1.0f) ? 0.5f * d * d : d - 0.5f;
                d = fabsf(pv.w - gv.w); sl1_sum += (d < 1.0f) ? 0.5f * d * d : d - 0.5f;
            }
        }
    }

    __shared__ double s_ce[4], s_sl[4];
    __shared__ unsigned int s_np[4];
    if (lane == 0) { s_ce[wid] = ce_sum; s_sl[wid] = sl1_sum; s_np[wid] = np; }
    __syncthreads();
    if (threadIdx.x == 0) {
        double c = 0.0, s = 0.0; unsigned int n = 0;
        for (int i = 0; i < 4; ++i) { c += s_ce[i]; s += s_sl[i]; n += s_np[i]; }
        atomicAdd(&acc[0], c);
        atomicAdd(&acc[1], s);
        atomicAdd((unsigned int*)(acc + 2), n);
    }
}

// One block per batch row: exact top-K sum of bg_loss among negatives via
// count-only radix select on monotone uint keys (bg >= 0 -> bits are ordered).
__global__ __launch_bounds__(1024) void mb_select(
    const float* __restrict__ bg,
    const int*   __restrict__ labels,
    double* __restrict__ acc)
{
    __shared__ unsigned int keys[NP];       // ~35 KB
    __shared__ unsigned int hist[256];
    __shared__ unsigned int s_part[16];
    __shared__ double s_sum[16];
    __shared__ unsigned int s_prefix, s_kleft;

    const int b   = blockIdx.x;
    const int tid = threadIdx.x;

    unsigned int np = 0;
    for (int i = tid; i < NP; i += 1024) {
        int lbl = labels[b * NP + i];
        float v = bg[b * NP + i];
        // negatives: bits+1 (>=1); positives: sentinel 0 (smallest)
        keys[i] = (lbl > 0) ? 0u : (__float_as_uint(v) + 1u);
        np += (lbl > 0) ? 1u : 0u;
    }
    #pragma unroll
    for (int o = 32; o; o >>= 1) np += __shfl_xor(np, o);
    if ((tid & 63) == 0) s_part[tid >> 6] = np;
    __syncthreads();
    if (tid == 0) {
        unsigned int t = 0;
        for (int i = 0; i < 16; ++i) t += s_part[i];
        unsigned int K = 3u * t;
        unsigned int nneg = NP - t;
        if (K > nneg) K = nneg;
        s_kleft = K;
        s_prefix = 0u;
    }
    __syncthreads();

    if (s_kleft > 0) {
        // 4-pass radix select for the K-th largest key
        for (int pass = 0; pass < 4; ++pass) {
            const int shift = 24 - 8 * pass;
            const unsigned int maskhi = (pass == 0) ? 0u : (0xFFFFFFFFu << (shift + 8));
            if (tid < 256) hist[tid] = 0u;
            __syncthreads();
            const unsigned int pfx = s_prefix;
            for (int i = tid; i < NP; i += 1024) {
                unsigned int k = keys[i];
                if (((k ^ pfx) & maskhi) == 0u)
                    atomicAdd(&hist[(k >> shift) & 255u], 1u);
            }
            __syncthreads();
            if (tid == 0) {
                unsigned int cum = 0; int j = 255;
                for (; j > 0; --j) {
                    unsigned int c = hist[j];
                    if (cum + c >= s_kleft) break;
                    cum += c;
                }
                s_prefix = pfx | ((unsigned int)j << shift);
                s_kleft -= cum;
            }
            __syncthreads();
        }

        const unsigned int T = s_prefix;    // exact key of K-th largest
        double accv = 0.0;
        for (int i = tid; i < NP; i += 1024) {
            unsigned int k = keys[i];
            if (k > T) accv += (double)__uint_as_float(k - 1u);
        }
        #pragma unroll
        for (int o = 32; o; o >>= 1) accv += __shfl_xor(accv, o);
        if ((tid & 63) == 0) s_sum[tid >> 6] = accv;
        __syncthreads();
        if (tid == 0) {
            double tot = 0.0;
            for (int i = 0; i < 16; ++i) tot += s_sum[i];
            // s_kleft now = count of keys equal to T still to select (tie-exact)
            tot += (double)s_kleft * (double)__uint_as_float(T - 1u);
            atomicAdd(&acc[0], tot);
        }
    }
}

__global__ void mb_final(const double* __restrict__ acc, float* __restrict__ out)
{
    unsigned int np = *(const unsigned int*)(acc + 2);
    float npf = (float)np;
    out[0] = (float)acc[1] / npf;   // smooth_l1_loss / num_pos
    out[1] = (float)acc[0] / npf;   // classification_loss / num_pos
}

extern "C" void kernel_launch(void* const* d_in, const int* in_sizes, int n_in,
                              void* d_out, int out_size, void* d_ws, size_t ws_size,
                              hipStream_t stream)
{
    const float* conf   = (const float*)d_in[0];
    const float* pred   = (const float*)d_in[1];
    const int*   labels = (const int*)d_in[2];
    const float* gt     = (const float*)d_in[3];
    float* out = (float*)d_out;

    double* acc = (double*)d_ws;
    float*  bg  = (float*)((char*)d_ws + 64);

    hipMemsetAsync(d_ws, 0, 64, stream);
    mb_rows<<<2048, 256, 0, stream>>>(conf, pred, gt, labels, bg, acc);
    mb_select<<<NB, 1024, 0, stream>>>(bg, labels, acc);
    mb_final<<<1, 1, 0, stream>>>(acc, out);
}

// Round 2
// 95.997 us; speedup vs baseline: 2.1785x; 2.1785x over previous
//
#include <hip/hip_runtime.h>
#include <math.h>

#define NB 64
#define NP 8732
#define NC 81
#define NROWS (NB * NP)
#define RPB 128                 // rows per block in mb_rows
#define TPB 256
#define NBLK (NROWS / RPB)      // 4366 (exact: 558848 = 4366*128)

// ws layout:
//   acc      : double[8]        @ 0      (acc[0] = top-K negative CE sum)
//   partials : double[NBLK*3]   @ 64     (ce_pos, sl1, num_pos per block)
//   bg       : float[NROWS]     @ 64 + NBLK*24
#define PART_OFF 64
#define BG_OFF   (64 + NBLK * 3 * 8)

__global__ __launch_bounds__(TPB) void mb_rows(
    const float* __restrict__ conf,
    const float* __restrict__ pred,
    const float* __restrict__ gt,
    const int*   __restrict__ labels,
    float* __restrict__ bg,
    double* __restrict__ partials)
{
    __shared__ float tile[RPB * NC];      // 41472 B, contiguous = global layout
    __shared__ double s_red[4][3];

    const int tid  = threadIdx.x;
    const int row0 = blockIdx.x * RPB;

    // ---- coalesced float4 stage of 128 rows (41472 B, 16B-aligned) ----
    const float4* s4 = (const float4*)(conf + (size_t)row0 * NC);
    float4* t4 = (float4*)tile;
    #pragma unroll
    for (int i = tid; i < RPB * NC / 4; i += TPB) t4[i] = s4[i];
    __syncthreads();

    // ---- half-row per thread: pair (2t,2t+1) owns row t ----
    const int r    = tid >> 1;
    const int h    = tid & 1;             // 0: classes 0..40, 1: classes 41..80
    const int row  = row0 + r;
    const float* rp = tile + r * NC;
    const int base = h * 41;

    float m = -3.4e38f;
    #pragma unroll
    for (int j = 0; j < 40; ++j) m = fmaxf(m, rp[base + j]);
    if (h == 0) m = fmaxf(m, rp[40]);

    const float M = fmaxf(m, __shfl_xor(m, 1));

    float s = 0.0f;
    #pragma unroll
    for (int j = 0; j < 40; ++j) s += __expf(rp[base + j] - M);
    if (h == 0) s += __expf(rp[40] - M);
    s += __shfl_xor(s, 1);

    const float lse = M + __logf(s);

    double ce = 0.0, sl = 0.0;
    int npos = 0;
    if (h == 0) {
        bg[row] = lse - rp[0];            // -log_softmax[..., 0]
        int lbl = labels[row];
        if (lbl > 0) {
            ce = (double)(lse - rp[lbl]);
            npos = 1;
            float4 pv = ((const float4*)pred)[row];
            float4 gv = ((const float4*)gt)[row];
            float d;
            d = fabsf(pv.x - gv.x); sl += (d < 1.0f) ? 0.5f * d * d : d - 0.5f;
            d = fabsf(pv.y - gv.y); sl += (d < 1.0f) ? 0.5f * d * d : d - 0.5f;
            d = fabsf(pv.z - gv.z); sl += (d < 1.0f) ? 0.5f * d * d : d - 0.5f;
            d = fabsf(pv.w - gv.w); sl += (d < 1.0f) ? 0.5f * d * d : d - 0.5f;
        }
    }

    // ---- block reduce -> one partials triple per block (no global atomics) ----
    #pragma unroll
    for (int o = 32; o; o >>= 1) {
        ce   += __shfl_xor(ce, o);
        sl   += __shfl_xor(sl, o);
        npos += __shfl_xor(npos, o);
    }
    const int wid = tid >> 6, lane = tid & 63;
    if (lane == 0) { s_red[wid][0] = ce; s_red[wid][1] = sl; s_red[wid][2] = (double)npos; }
    __syncthreads();
    if (tid == 0) {
        double a = 0, b = 0, c = 0;
        for (int w = 0; w < 4; ++w) { a += s_red[w][0]; b += s_red[w][1]; c += s_red[w][2]; }
        partials[blockIdx.x * 3 + 0] = a;
        partials[blockIdx.x * 3 + 1] = b;
        partials[blockIdx.x * 3 + 2] = c;
    }
}

// One block per batch row: exact top-K sum of bg among negatives.
// Atomic-free: 32-step binary search over the uint key space for the K-th
// largest key (exact, tie-correct), then one sum pass.
__global__ __launch_bounds__(1024) void mb_select(
    const float* __restrict__ bg,
    const int*   __restrict__ labels,
    double* __restrict__ acc)
{
    __shared__ unsigned keys[NP];         // ~35 KB
    __shared__ unsigned s_part[16];
    __shared__ double   s_sum[16];
    __shared__ unsigned s_cnt2[16];
    __shared__ unsigned s_tot;

    const int b = blockIdx.x, tid = threadIdx.x;

    unsigned np = 0;
    for (int i = tid; i < NP; i += 1024) {
        int   lbl = labels[b * NP + i];
        float v   = bg[b * NP + i];
        // negatives: bits+1 (>=1, order-preserving since bg>=0); positives: 0
        keys[i] = (lbl > 0) ? 0u : (__float_as_uint(v) + 1u);
        np += (lbl > 0) ? 1u : 0u;
    }
    #pragma unroll
    for (int o = 32; o; o >>= 1) np += __shfl_xor(np, o);
    if ((tid & 63) == 0) s_part[tid >> 6] = np;
    __syncthreads();
    if (tid == 0) {
        unsigned t = 0;
        for (int i = 0; i < 16; ++i) t += s_part[i];
        s_tot = t;
    }
    __syncthreads();

    const unsigned npos_tot = s_tot;
    unsigned K = 3u * npos_tot;
    const unsigned nneg = NP - npos_tot;
    if (K > nneg) K = nneg;
    if (K == 0) return;

    // binary search: smallest x with count(key > x) < K  ->  x = K-th largest key
    unsigned lo = 0u, hi = 0xFFFFFFFFu;
    while (lo < hi) {
        const unsigned mid = lo + ((hi - lo) >> 1);
        unsigned c = 0;
        for (int i = tid; i < NP; i += 1024) c += (keys[i] > mid) ? 1u : 0u;
        #pragma unroll
        for (int o = 32; o; o >>= 1) c += __shfl_xor(c, o);
        __syncthreads();                       // protect s_part from prev iter
        if ((tid & 63) == 0) s_part[tid >> 6] = c;
        __syncthreads();
        if (tid == 0) {
            unsigned t = 0;
            for (int i = 0; i < 16; ++i) t += s_part[i];
            s_tot = t;
        }
        __syncthreads();
        if (s_tot < K) hi = mid; else lo = mid + 1;
    }
    const unsigned V = lo;                     // guaranteed an existing key, >= 1

    double s = 0.0;
    unsigned cgt = 0;
    for (int i = tid; i < NP; i += 1024) {
        unsigned k = keys[i];
        if (k > V) { s += (double)__uint_as_float(k - 1u); cgt++; }
    }
    #pragma unroll
    for (int o = 32; o; o >>= 1) { s += __shfl_xor(s, o); cgt += __shfl_xor(cgt, o); }
    if ((tid & 63) == 0) { s_sum[tid >> 6] = s; s_cnt2[tid >> 6] = cgt; }
    __syncthreads();
    if (tid == 0) {
        double tot = 0.0; unsigned cg = 0;
        for (int i = 0; i < 16; ++i) { tot += s_sum[i]; cg += s_cnt2[i]; }
        tot += (double)(K - cg) * (double)__uint_as_float(V - 1u);  // ties at V
        atomicAdd(&acc[0], tot);
    }
}

__global__ __launch_bounds__(1024) void mb_final(
    const double* __restrict__ acc,
    const double* __restrict__ partials,
    float* __restrict__ out)
{
    __shared__ double s_r[16][3];
    const int tid = threadIdx.x;
    double ce = 0, sl = 0, np = 0;
    for (int i = tid; i < NBLK; i += 1024) {
        ce += partials[3 * i + 0];
        sl += partials[3 * i + 1];
        np += partials[3 * i + 2];
    }
    #pragma unroll
    for (int o = 32; o; o >>= 1) {
        ce += __shfl_xor(ce, o);
        sl += __shfl_xor(sl, o);
        np += __shfl_xor(np, o);
    }
    if ((tid & 63) == 0) { s_r[tid >> 6][0] = ce; s_r[tid >> 6][1] = sl; s_r[tid >> 6][2] = np; }
    __syncthreads();
    if (tid == 0) {
        double a = 0, b = 0, c = 0;
        for (int w = 0; w < 16; ++w) { a += s_r[w][0]; b += s_r[w][1]; c += s_r[w][2]; }
        const double cls = a + acc[0];
        const float npf = (float)c;
        out[0] = (float)b   / npf;   // smooth_l1_loss / num_pos
        out[1] = (float)cls / npf;   // classification_loss / num_pos
    }
}

extern "C" void kernel_launch(void* const* d_in, const int* in_sizes, int n_in,
                              void* d_out, int out_size, void* d_ws, size_t ws_size,
                              hipStream_t stream)
{
    const float* conf   = (const float*)d_in[0];
    const float* pred   = (const float*)d_in[1];
    const int*   labels = (const int*)d_in[2];
    const float* gt     = (const float*)d_in[3];
    float* out = (float*)d_out;

    double* acc      = (double*)d_ws;
    double* partials = (double*)((char*)d_ws + PART_OFF);
    float*  bg       = (float*)((char*)d_ws + BG_OFF);

    hipMemsetAsync(d_ws, 0, 64, stream);
    mb_rows<<<NBLK, TPB, 0, stream>>>(conf, pred, gt, labels, bg, partials);
    mb_select<<<NB, 1024, 0, stream>>>(bg, labels, acc);
    mb_final<<<1, 1024, 0, stream>>>(acc, partials, out);
}